// Round 13
// baseline (102.537 us; speedup 1.0000x reference)
//
#include <hip/hip_runtime.h>
#include <hip/hip_bf16.h>

// MMD loss via bf16 MFMA Gram matrix.
// R13: K-chunk 32 -> 64 (4 sync events per tile instead of 8). Ledger:
// traffic/occupancy/depth/barrier-flavor/address-order all neutral (R4-R12);
// only event-count was never varied, and R9 (+1 barrier/chunk) cost ~8us ->
// per-event fixed drain ~1-2k cyc. This round halves events.
// 2-slot double buffer (64KB LDS, 2 blk/CU unchanged - VGPR caps us at
// 2 waves/SIMD anyway). STAGE into the just-consumed slot is placed AFTER
// the barrier (all waves consumed it -> no WAR race; that is why 2 slots
// suffice where the 32-wide pipe needed 3).
//
// Zc layout: Zc[ck][row][32] (ck=0..7 of K=32), stored quad = q^((row>>1)&3);
// a K64 chunk c = phys chunks {2c,2c+1}, staged as two 8KB sub-panels.
// Lessons: no __threadfence; no scattered vector loads; no s_barrier align
// of reg streams (R3); no 1 wave/SIMD (R4); compiler re-sinks deep register
// pipelines (R11); L2 hotspot rotation neutral (R12).
//
// z = [xf; yf] (8192 x 256). result = (1/4096^2)*(8192*NSIG + sum_{i<j} 2 s_i s_j K_ij)
// ws: [0,4MiB) bf16 Zc; float norms[8192]; float partials[2080].

#define NSIG 5
#define CKS   262144                 // chunk stride in ushorts: 8192 rows * 32
#define NBLK2 2080                   // 64-supergrid triangle: 64*65/2

typedef __attribute__((ext_vector_type(8))) short short8;
typedef __attribute__((ext_vector_type(4))) float floatx4;

#define GLDS16(gp, lp) __builtin_amdgcn_global_load_lds( \
    (const __attribute__((address_space(1))) void*)(gp),  \
    (__attribute__((address_space(3))) void*)(lp), 16, 0, 0)

// ---- prep: (B,C,H,W) fp32 -> Zc chunked-swizzled bf16 + norms (unchanged) ----
__global__ __launch_bounds__(256) void prep_kernel(const float* __restrict__ x,
                                                   const float* __restrict__ y,
                                                   ushort* __restrict__ Zc,
                                                   float* __restrict__ norms) {
    const int bid = blockIdx.x;           // s(1) | b(2) | strip(6)
    const int t = threadIdx.x;
    const int s = bid >> 8;
    const int b = (bid >> 6) & 3;
    const int p0 = (bid & 63) << 4;
    const float* src = s ? y : x;
    const int n0 = (s << 12) + (b << 10) + p0;

    __shared__ float tile[256][17];

    const int cg = t >> 2;
    const int p4 = (t & 3) << 2;
#pragma unroll
    for (int pass = 0; pass < 4; ++pass) {
        const int c = cg + (pass << 6);
        const float4 v = *(const float4*)(src + (((size_t)((b << 8) + c)) << 10) + p0 + p4);
        tile[c][p4] = v.x; tile[c][p4 + 1] = v.y; tile[c][p4 + 2] = v.z; tile[c][p4 + 3] = v.w;
    }
    __syncthreads();

    const int r = t >> 4;
    const int q = t & 15;
    const int row = n0 + r;
    const int sw = (row >> 1) & 3;
    float nsum = 0.f;
#pragma unroll
    for (int h = 0; h < 2; ++h) {
        const int j = q + (h << 4);
        const int ck = j >> 2;
        const int sq = (j & 3) ^ sw;
        const int c0 = j << 3;
        uint pk[4];
#pragma unroll
        for (int jj = 0; jj < 4; ++jj) {
            const float f0 = tile[c0 + 2 * jj][r];
            const float f1 = tile[c0 + 2 * jj + 1][r];
            const __hip_bfloat16 h0 = __float2bfloat16(f0);
            const __hip_bfloat16 h1 = __float2bfloat16(f1);
            const float q0 = __bfloat162float(h0), q1 = __bfloat162float(h1);
            nsum = fmaf(q0, q0, nsum);
            nsum = fmaf(q1, q1, nsum);
            pk[jj] = (uint)(*(const ushort*)&h0) | ((uint)(*(const ushort*)&h1) << 16);
        }
        *(uint4*)(Zc + (size_t)ck * CKS + (size_t)row * 32 + (sq << 3)) =
            make_uint4(pk[0], pk[1], pk[2], pk[3]);
    }
#pragma unroll
    for (int off = 1; off < 16; off <<= 1) nsum += __shfl_xor(nsum, off, 32);
    if (q == 0) norms[row] = nsum;
}

// ---- GEMM: 4-wave blocks, 128x128 supertile, K64 chunks, 2-slot dbuf ----
__global__ __launch_bounds__(256) void gemm_epi(const ushort* __restrict__ Zc,
                                                const float* __restrict__ norms,
                                                const float* __restrict__ sigmas,
                                                float* __restrict__ partials) {
    __shared__ ushort bufA[2][2][4096];   // [slot][ksub][8KB]: A panels (32KB)
    __shared__ ushort bufB[2][2][4096];   // [slot][ksub][8KB]: B panels (32KB)
    __shared__ float wsum[4];

    const int t = threadIdx.x;
    const int w = t >> 6, l = t & 63;
    const int m = l & 15, q = l >> 4;

    // panel decode: panels p of 8 super-columns; P(p) = 32p^2 + 4p blocks before
    // panel p; within panel, column-major (column tj2 has tj2+1 blocks).
    const int lin = blockIdx.x;
    int p = (int)((-4.0f + sqrtf(16.0f + 128.0f * (float)lin)) * (1.0f / 64.0f));
    p = p < 0 ? 0 : (p > 7 ? 7 : p);
    while (p < 7 && 32 * (p + 1) * (p + 1) + 4 * (p + 1) <= lin) ++p;
    while (p > 0 && 32 * p * p + 4 * p > lin) --p;
    const int o = lin - (32 * p * p + 4 * p);
    int c = 7;
#pragma unroll
    for (int cc = 7; cc >= 1; --cc) {
        const int Q = cc * (8 * p + 1) + (cc * (cc - 1)) / 2;
        if (o < Q) c = cc - 1;
    }
    const int Qc = c * (8 * p + 1) + (c * (c - 1)) / 2;
    const int tj2 = 8 * p + c;
    const int ti2 = o - Qc;              // 0..tj2

    const int I0 = ti2 << 7;             // supertile bases (multiples of 128)
    const int J0 = tj2 << 7;

    // wave quadrant: ti = 2*ti2 + (w>>1), tj = 2*tj2 + (w&1)
    const int ti = (ti2 << 1) + (w >> 1);
    const int tj = (tj2 << 1) + (w & 1);
    const bool active = (ti <= tj);      // lower-tri wave of diag supertile: discard
    const bool diag = (ti == tj);
    const int i0 = ti << 6, j0 = tj << 6;

    // LDS fragment read offsets (ushort idx, panel-local rows within a sub-panel)
    int loffA[4], loffB[4];
#pragma unroll
    for (int f = 0; f < 4; ++f) {
        const int ra = ((w >> 1) << 6) + (f << 4) + m;
        loffA[f] = (ra << 5) + ((q ^ ((ra >> 1) & 3)) << 3);
        const int rb = ((w & 1) << 6) + (f << 4) + m;
        loffB[f] = (rb << 5) + ((q ^ ((rb >> 1) & 3)) << 3);
    }

    // staging: wave w copies ushorts [w*1024,(w+1)*1024) of each 8KB sub-panel,
    // 2 glds per sub-panel per matrix -> 8 glds/wave per K64 chunk.
    const int sg = (w << 10) + (l << 3);
    const ushort* gA0 = Zc + (size_t)I0 * 32 + sg;
    const ushort* gB0 = Zc + (size_t)J0 * 32 + sg;
    const int lo = w << 10;

#define STAGE64(c_, s_) do {                                              \
        const size_t k0_ = (size_t)(2 * (c_)) * CKS;                      \
        const size_t k1_ = (size_t)(2 * (c_) + 1) * CKS;                  \
        GLDS16(gA0 + k0_,       &bufA[s_][0][lo]);                        \
        GLDS16(gA0 + k0_ + 512, &bufA[s_][0][lo + 512]);                  \
        GLDS16(gA0 + k1_,       &bufA[s_][1][lo]);                        \
        GLDS16(gA0 + k1_ + 512, &bufA[s_][1][lo + 512]);                  \
        GLDS16(gB0 + k0_,       &bufB[s_][0][lo]);                        \
        GLDS16(gB0 + k0_ + 512, &bufB[s_][0][lo + 512]);                  \
        GLDS16(gB0 + k1_,       &bufB[s_][1][lo]);                        \
        GLDS16(gB0 + k1_ + 512, &bufB[s_][1][lo + 512]);                  \
    } while (0)

    // prologue: slot0 <- chunk0, slot1 <- chunk1; wait chunk0 only (8 left)
    STAGE64(0, 0);
    STAGE64(1, 1);
    asm volatile("s_waitcnt vmcnt(8)" ::: "memory");
    __builtin_amdgcn_s_barrier();
    __builtin_amdgcn_sched_barrier(0);

    floatx4 accf[4][4];
#pragma unroll
    for (int fi = 0; fi < 4; ++fi)
#pragma unroll
        for (int fj = 0; fj < 4; ++fj) accf[fi][fj] = (floatx4){0.f, 0.f, 0.f, 0.f};

    // ---- main K loop: 4 chunks of K=64; one wait+barrier per chunk;
    // ---- stage into just-consumed slot AFTER the barrier (no WAR race).
#pragma unroll
    for (int ck = 0; ck < 4; ++ck) {
        const int sl = ck & 1;
        short8 fa[2][4], fb[2][4];
#pragma unroll
        for (int s = 0; s < 2; ++s) {
#pragma unroll
            for (int f = 0; f < 4; ++f) {
                fa[s][f] = *(const short8*)(&bufA[sl][s][0] + loffA[f]);
                fb[s][f] = *(const short8*)(&bufB[sl][s][0] + loffB[f]);
            }
        }
#pragma unroll
        for (int s = 0; s < 2; ++s)
#pragma unroll
            for (int fi = 0; fi < 4; ++fi)
#pragma unroll
                for (int fj = 0; fj < 4; ++fj)
                    accf[fi][fj] = __builtin_amdgcn_mfma_f32_16x16x32_bf16(
                        fa[s][fi], fb[s][fj], accf[fi][fj], 0, 0, 0);
        if (ck < 3) {
            asm volatile("s_waitcnt vmcnt(0)" ::: "memory");  // next slot ready
            __builtin_amdgcn_s_barrier();                     // all waves done with sl
            __builtin_amdgcn_sched_barrier(0);
            if (ck < 2) STAGE64(ck + 2, sl);                  // refill consumed slot
        }
    }
#undef STAGE64

    // ---- epilogue: chain-parallel, vector-shaped (R10) ----
    float lsum = 0.f;
    if (active) {
        float c2[NSIG];
#pragma unroll
        for (int k = 0; k < NSIG; ++k) c2[k] = (-0.5f / sigmas[k]) * 1.44269504f;

        const float sgn2 = ((i0 < 4096) == (j0 < 4096)) ? 2.f : -2.f;

        float njs[4];
#pragma unroll
        for (int fj = 0; fj < 4; ++fj) njs[fj] = norms[j0 + (fj << 4) + m];

        // d = max(ni + nj - 2*g, 0) — vector-shaped, no per-element branch
#pragma unroll
        for (int fi = 0; fi < 4; ++fi) {
            const floatx4 ni4 = *(const floatx4*)(norms + i0 + (fi << 4) + (q << 2));
#pragma unroll
            for (int fj = 0; fj < 4; ++fj) {
                floatx4 a = accf[fi][fj];
#pragma unroll
                for (int v = 0; v < 4; ++v)
                    a[v] = fmaxf(fmaf(-2.f, a[v], ni4[v] + njs[fj]), 0.f);
                accf[fi][fj] = a;
            }
        }
        if (diag) {        // wave-uniform rare path: strictly-upper mask
#pragma unroll
            for (int fi = 0; fi < 4; ++fi)
#pragma unroll
                for (int fj = 0; fj < 4; ++fj)
#pragma unroll
                    for (int v = 0; v < 4; ++v) {
                        const int dif = ((fi - fj) << 4) + ((q << 2) + v) - m;   // gi - gj
                        if (dif >= 0) accf[fi][fj][v] = 3.0e9f;
                    }
        }

        // dmin: 4 independent component chains, then 2-level tree + shfl
        floatx4 mn = accf[0][0];
#pragma unroll
        for (int fi = 0; fi < 4; ++fi)
#pragma unroll
            for (int fj = 0; fj < 4; ++fj)
                if (fi | fj) {
#pragma unroll
                    for (int v = 0; v < 4; ++v) mn[v] = fminf(mn[v], accf[fi][fj][v]);
                }
        float dmin = fminf(fminf(mn[0], mn[1]), fminf(mn[2], mn[3]));
#pragma unroll
        for (int off = 1; off < 64; off <<= 1) dmin = fminf(dmin, __shfl_xor(dmin, off, 64));

        // exp accumulate: 8 independent chains (two floatx4 accumulators)
        floatx4 ts0 = (floatx4){0.f, 0.f, 0.f, 0.f};
        floatx4 ts1 = (floatx4){0.f, 0.f, 0.f, 0.f};
#pragma unroll
        for (int k = 0; k < NSIG; ++k) {
            if (c2[k] * dmin >= -126.f) {   // wave-uniform skip iff all exps underflow
                const float ck2 = c2[k];
#pragma unroll
                for (int fi = 0; fi < 4; ++fi)
#pragma unroll
                    for (int fj = 0; fj < 4; ++fj) {
                        const floatx4 a = accf[fi][fj];
                        floatx4 e;
#pragma unroll
                        for (int v = 0; v < 4; ++v)
                            e[v] = __builtin_amdgcn_exp2f(ck2 * a[v]);
                        if ((fj & 1) == 0) ts0 += e; else ts1 += e;
                    }
            }
        }
        ts0 += ts1;
        lsum = sgn2 * ((ts0[0] + ts0[1]) + (ts0[2] + ts0[3]));
    }

    // ---- block reduce + store ----
#pragma unroll
    for (int off = 32; off > 0; off >>= 1) lsum += __shfl_down(lsum, off, 64);
    if (l == 0) wsum[w] = lsum;
    __syncthreads();
    if (t == 0) partials[blockIdx.x] = wsum[0] + wsum[1] + wsum[2] + wsum[3];
}

__global__ __launch_bounds__(256) void finalize_kernel(const float* __restrict__ partials,
                                                       float* __restrict__ out) {
    __shared__ double sh[256];
    const int t = threadIdx.x;
    double s = 0.0;
    for (int i = t; i < NBLK2; i += 256) s += (double)partials[i];
    sh[t] = s;
    __syncthreads();
    for (int st = 128; st > 0; st >>= 1) {
        if (t < st) sh[t] += sh[t + st];
        __syncthreads();
    }
    if (t == 0) out[0] = (float)((sh[0] + 8192.0 * NSIG) * (1.0 / (4096.0 * 4096.0)));
}

extern "C" void kernel_launch(void* const* d_in, const int* in_sizes, int n_in,
                              void* d_out, int out_size, void* d_ws, size_t ws_size,
                              hipStream_t stream) {
    const float* x   = (const float*)d_in[0];
    const float* y   = (const float*)d_in[1];
    const float* sig = (const float*)d_in[2];

    ushort* Zc      = (ushort*)d_ws;                                   // 4 MiB
    float* norms    = (float*)((char*)d_ws + (size_t)8192 * 256 * 2);  // 32 KiB
    float* partials = (float*)((char*)norms + 8192 * sizeof(float));   // 2080 floats
    float* out      = (float*)d_out;

    prep_kernel<<<512, 256, 0, stream>>>(x, y, Zc, norms);
    gemm_epi<<<NBLK2, 256, 0, stream>>>(Zc, norms, sig, partials);
    finalize_kernel<<<1, 256, 0, stream>>>(partials, out);
}

// Round 14
// 99.873 us; speedup vs baseline: 1.0267x; 1.0267x over previous
//
#include <hip/hip_runtime.h>
#include <hip/hip_bf16.h>

// MMD loss via bf16 MFMA Gram matrix.
// R14: occupancy UP — the one untested axis. All variants sat at ~2 waves/
// SIMD (unified VGPR ~132-148 = arch ~68 + acc 64). Halve the accumulator:
// 32x64 wave tiles (acc 32 VGPR, unified ~95 < 128) -> 4 waves/SIMD per
// m69's occupancy steps. 128x128 supertile kept: 512-thread blocks, 8 waves
// of 32x64. R10's 3-buffer counted-vmcnt LDS ring unchanged; staging is now
// 1KB glds per wave per panel (2 glds/chunk/wave). LDS 49KB -> 2 blk/CU =
// 16 waves/CU (2x TLP vs R10).
// R13 lesson: K64 chunks regressed (+8us) - event-count theory dead.
// R11 lesson: compiler re-sinks register pipelines. R4: occupancy DOWN bad.
//
// Zc layout: Zc[ck][row][32], stored quad = q ^ ((row>>1)&3); 128-row panel
// per chunk = contiguous 8KB; supertile base % 128 == 0 keeps the swizzle
// valid on LDS-local rows. glds: wave-uniform LDS base + lane*16B.
//
// z = [xf; yf] (8192 x 256). result = (1/4096^2)*(8192*NSIG + sum_{i<j} 2 s_i s_j K_ij)
// ws: [0,4MiB) bf16 Zc; float norms[8192]; float partials[2080].

#define NSIG 5
#define CKS   262144                 // chunk stride in ushorts: 8192 rows * 32
#define NBLK2 2080                   // 64-supergrid triangle: 64*65/2

typedef __attribute__((ext_vector_type(8))) short short8;
typedef __attribute__((ext_vector_type(4))) float floatx4;

#define GLDS16(gp, lp) __builtin_amdgcn_global_load_lds( \
    (const __attribute__((address_space(1))) void*)(gp),  \
    (__attribute__((address_space(3))) void*)(lp), 16, 0, 0)

// ---- prep: (B,C,H,W) fp32 -> Zc chunked-swizzled bf16 + norms (unchanged) ----
__global__ __launch_bounds__(256) void prep_kernel(const float* __restrict__ x,
                                                   const float* __restrict__ y,
                                                   ushort* __restrict__ Zc,
                                                   float* __restrict__ norms) {
    const int bid = blockIdx.x;           // s(1) | b(2) | strip(6)
    const int t = threadIdx.x;
    const int s = bid >> 8;
    const int b = (bid >> 6) & 3;
    const int p0 = (bid & 63) << 4;
    const float* src = s ? y : x;
    const int n0 = (s << 12) + (b << 10) + p0;

    __shared__ float tile[256][17];

    const int cg = t >> 2;
    const int p4 = (t & 3) << 2;
#pragma unroll
    for (int pass = 0; pass < 4; ++pass) {
        const int c = cg + (pass << 6);
        const float4 v = *(const float4*)(src + (((size_t)((b << 8) + c)) << 10) + p0 + p4);
        tile[c][p4] = v.x; tile[c][p4 + 1] = v.y; tile[c][p4 + 2] = v.z; tile[c][p4 + 3] = v.w;
    }
    __syncthreads();

    const int r = t >> 4;
    const int q = t & 15;
    const int row = n0 + r;
    const int sw = (row >> 1) & 3;
    float nsum = 0.f;
#pragma unroll
    for (int h = 0; h < 2; ++h) {
        const int j = q + (h << 4);
        const int ck = j >> 2;
        const int sq = (j & 3) ^ sw;
        const int c0 = j << 3;
        uint pk[4];
#pragma unroll
        for (int jj = 0; jj < 4; ++jj) {
            const float f0 = tile[c0 + 2 * jj][r];
            const float f1 = tile[c0 + 2 * jj + 1][r];
            const __hip_bfloat16 h0 = __float2bfloat16(f0);
            const __hip_bfloat16 h1 = __float2bfloat16(f1);
            const float q0 = __bfloat162float(h0), q1 = __bfloat162float(h1);
            nsum = fmaf(q0, q0, nsum);
            nsum = fmaf(q1, q1, nsum);
            pk[jj] = (uint)(*(const ushort*)&h0) | ((uint)(*(const ushort*)&h1) << 16);
        }
        *(uint4*)(Zc + (size_t)ck * CKS + (size_t)row * 32 + (sq << 3)) =
            make_uint4(pk[0], pk[1], pk[2], pk[3]);
    }
#pragma unroll
    for (int off = 1; off < 16; off <<= 1) nsum += __shfl_xor(nsum, off, 32);
    if (q == 0) norms[row] = nsum;
}

// ---- GEMM: 8-wave blocks (512 thr), 32x64 wave tiles, 128x128 supertile,
// ----       3-buffer counted-vmcnt LDS ring (R10 schedule) ----
__global__ __launch_bounds__(512) void gemm_epi(const ushort* __restrict__ Zc,
                                                const float* __restrict__ norms,
                                                const float* __restrict__ sigmas,
                                                float* __restrict__ partials) {
    __shared__ ushort bufA[3][4096];   // 3 x 8KB: A panel (128 rows x 32)
    __shared__ ushort bufB[3][4096];   // 3 x 8KB: B panel
    __shared__ float wsum[8];

    const int t = threadIdx.x;
    const int w = t >> 6, l = t & 63;
    const int m = l & 15, q = l >> 4;

    // panel decode: panels p of 8 super-columns; P(p) = 32p^2 + 4p blocks before
    // panel p; within panel, column-major (column tj2 has tj2+1 blocks).
    const int lin = blockIdx.x;
    int p = (int)((-4.0f + sqrtf(16.0f + 128.0f * (float)lin)) * (1.0f / 64.0f));
    p = p < 0 ? 0 : (p > 7 ? 7 : p);
    while (p < 7 && 32 * (p + 1) * (p + 1) + 4 * (p + 1) <= lin) ++p;
    while (p > 0 && 32 * p * p + 4 * p > lin) --p;
    const int o = lin - (32 * p * p + 4 * p);
    int c = 7;
#pragma unroll
    for (int cc = 7; cc >= 1; --cc) {
        const int Q = cc * (8 * p + 1) + (cc * (cc - 1)) / 2;
        if (o < Q) c = cc - 1;
    }
    const int Qc = c * (8 * p + 1) + (c * (c - 1)) / 2;
    const int tj2 = 8 * p + c;
    const int ti2 = o - Qc;              // 0..tj2
    const bool diagST = (ti2 == tj2);

    const int I0 = ti2 << 7;             // supertile bases (multiples of 128)
    const int J0 = tj2 << 7;

    // wave -> 32x64 tile: row strip r = w>>1 (32 rows), col strip cc2 = w&1 (64 cols)
    const int rs = w >> 1;               // 0..3
    const int cs = w & 1;                // 0..1
    // diag supertile: discard fully-lower tiles (rows all > cols)
    const bool active = !(diagST && cs == 0 && rs >= 2);
    const int i0 = I0 + (rs << 5);       // global row base (32 rows)
    const int j0 = J0 + (cs << 6);       // global col base (64 cols)

    // LDS fragment read offsets (ushort idx, panel-local rows)
    int loffA[2], loffB[4];
#pragma unroll
    for (int f = 0; f < 2; ++f) {
        const int ra = (rs << 5) + (f << 4) + m;
        loffA[f] = (ra << 5) + ((q ^ ((ra >> 1) & 3)) << 3);
    }
#pragma unroll
    for (int f = 0; f < 4; ++f) {
        const int rb = (cs << 6) + (f << 4) + m;
        loffB[f] = (rb << 5) + ((q ^ ((rb >> 1) & 3)) << 3);
    }

    // staging: wave w copies the w-th KB of each 8KB panel: 1 glds/panel/wave.
    const int sg = (w << 9) + (l << 3);
    const ushort* gA0 = Zc + (size_t)I0 * 32 + sg;
    const ushort* gB0 = Zc + (size_t)J0 * 32 + sg;
    const int lo = w << 9;

    // prologue: stage ck0 -> buf0 (oldest 2), ck1 -> buf1; wait ck0 only.
    GLDS16(gA0,       &bufA[0][lo]);
    GLDS16(gB0,       &bufB[0][lo]);
    GLDS16(gA0 + CKS, &bufA[1][lo]);
    GLDS16(gB0 + CKS, &bufB[1][lo]);
    asm volatile("s_waitcnt vmcnt(2)" ::: "memory");
    __builtin_amdgcn_s_barrier();
    __builtin_amdgcn_sched_barrier(0);

    floatx4 accf[2][4];
#pragma unroll
    for (int fi = 0; fi < 2; ++fi)
#pragma unroll
        for (int fj = 0; fj < 4; ++fj) accf[fi][fj] = (floatx4){0.f, 0.f, 0.f, 0.f};

    // ---- main K loop: 8 chunks, depth-2 glds, counted vmcnt, raw barrier ----
#pragma unroll
    for (int ck = 0; ck < 8; ++ck) {
        const ushort* rA = &bufA[ck % 3][0];
        const ushort* rB = &bufB[ck % 3][0];
        short8 fa[2], fb[4];
#pragma unroll
        for (int f = 0; f < 2; ++f) fa[f] = *(const short8*)(rA + loffA[f]);
#pragma unroll
        for (int f = 0; f < 4; ++f) fb[f] = *(const short8*)(rB + loffB[f]);
        if (ck < 6) {
            const size_t ko = (size_t)(ck + 2) * CKS;
            const int nb = (ck + 2) % 3;
            GLDS16(gA0 + ko, &bufA[nb][lo]);
            GLDS16(gB0 + ko, &bufB[nb][lo]);
        }
#pragma unroll
        for (int fi = 0; fi < 2; ++fi)
#pragma unroll
            for (int fj = 0; fj < 4; ++fj)
                accf[fi][fj] = __builtin_amdgcn_mfma_f32_16x16x32_bf16(fa[fi], fb[fj], accf[fi][fj], 0, 0, 0);
        if (ck < 7) {
            if (ck < 6) { asm volatile("s_waitcnt vmcnt(2)" ::: "memory"); }
            else        { asm volatile("s_waitcnt vmcnt(0)" ::: "memory"); }
            __builtin_amdgcn_s_barrier();
            __builtin_amdgcn_sched_barrier(0);
        }
    }

    // ---- epilogue: chain-parallel, vector-shaped (R10 form) ----
    float lsum = 0.f;
    if (active) {
        float c2[NSIG];
#pragma unroll
        for (int k = 0; k < NSIG; ++k) c2[k] = (-0.5f / sigmas[k]) * 1.44269504f;

        const float sgn2 = ((i0 < 4096) == (j0 < 4096)) ? 2.f : -2.f;

        float njs[4];
#pragma unroll
        for (int fj = 0; fj < 4; ++fj) njs[fj] = norms[j0 + (fj << 4) + m];

        // d = max(ni + nj - 2*g, 0) — vector-shaped
#pragma unroll
        for (int fi = 0; fi < 2; ++fi) {
            const floatx4 ni4 = *(const floatx4*)(norms + i0 + (fi << 4) + (q << 2));
#pragma unroll
            for (int fj = 0; fj < 4; ++fj) {
                floatx4 a = accf[fi][fj];
#pragma unroll
                for (int v = 0; v < 4; ++v)
                    a[v] = fmaxf(fmaf(-2.f, a[v], ni4[v] + njs[fj]), 0.f);
                accf[fi][fj] = a;
            }
        }
        if (diagST) {      // wave-uniform rare path: strictly-upper mask
                           // gi = rs*32 + fi*16 + q*4 + v; gj = cs*64 + fj*16 + m
#pragma unroll
            for (int fi = 0; fi < 2; ++fi)
#pragma unroll
                for (int fj = 0; fj < 4; ++fj)
#pragma unroll
                    for (int v = 0; v < 4; ++v) {
                        const int dif = (rs << 5) + (fi << 4) + (q << 2) + v
                                      - (cs << 6) - (fj << 4) - m;
                        if (dif >= 0) accf[fi][fj][v] = 3.0e9f;
                    }
        }

        // dmin: component chains + tree + shfl
        floatx4 mn = accf[0][0];
#pragma unroll
        for (int fi = 0; fi < 2; ++fi)
#pragma unroll
            for (int fj = 0; fj < 4; ++fj)
                if (fi | fj) {
#pragma unroll
                    for (int v = 0; v < 4; ++v) mn[v] = fminf(mn[v], accf[fi][fj][v]);
                }
        float dmin = fminf(fminf(mn[0], mn[1]), fminf(mn[2], mn[3]));
#pragma unroll
        for (int off = 1; off < 64; off <<= 1) dmin = fminf(dmin, __shfl_xor(dmin, off, 64));

        // exp accumulate: 8 independent chains (two floatx4 accumulators)
        floatx4 ts0 = (floatx4){0.f, 0.f, 0.f, 0.f};
        floatx4 ts1 = (floatx4){0.f, 0.f, 0.f, 0.f};
#pragma unroll
        for (int k = 0; k < NSIG; ++k) {
            if (c2[k] * dmin >= -126.f) {   // wave-uniform skip iff all exps underflow
                const float ck2 = c2[k];
#pragma unroll
                for (int fi = 0; fi < 2; ++fi)
#pragma unroll
                    for (int fj = 0; fj < 4; ++fj) {
                        const floatx4 a = accf[fi][fj];
                        floatx4 e;
#pragma unroll
                        for (int v = 0; v < 4; ++v)
                            e[v] = __builtin_amdgcn_exp2f(ck2 * a[v]);
                        if ((fj & 1) == 0) ts0 += e; else ts1 += e;
                    }
            }
        }
        ts0 += ts1;
        lsum = sgn2 * ((ts0[0] + ts0[1]) + (ts0[2] + ts0[3]));
    }

    // ---- block reduce + store ----
#pragma unroll
    for (int off = 32; off > 0; off >>= 1) lsum += __shfl_down(lsum, off, 64);
    if (l == 0) wsum[w] = lsum;
    __syncthreads();
    if (t == 0) {
        float s = 0.f;
#pragma unroll
        for (int i = 0; i < 8; ++i) s += wsum[i];
        partials[blockIdx.x] = s;
    }
}

__global__ __launch_bounds__(256) void finalize_kernel(const float* __restrict__ partials,
                                                       float* __restrict__ out) {
    __shared__ double sh[256];
    const int t = threadIdx.x;
    double s = 0.0;
    for (int i = t; i < NBLK2; i += 256) s += (double)partials[i];
    sh[t] = s;
    __syncthreads();
    for (int st = 128; st > 0; st >>= 1) {
        if (t < st) sh[t] += sh[t + st];
        __syncthreads();
    }
    if (t == 0) out[0] = (float)((sh[0] + 8192.0 * NSIG) * (1.0 / (4096.0 * 4096.0)));
}

extern "C" void kernel_launch(void* const* d_in, const int* in_sizes, int n_in,
                              void* d_out, int out_size, void* d_ws, size_t ws_size,
                              hipStream_t stream) {
    const float* x   = (const float*)d_in[0];
    const float* y   = (const float*)d_in[1];
    const float* sig = (const float*)d_in[2];

    ushort* Zc      = (ushort*)d_ws;                                   // 4 MiB
    float* norms    = (float*)((char*)d_ws + (size_t)8192 * 256 * 2);  // 32 KiB
    float* partials = (float*)((char*)norms + 8192 * sizeof(float));   // 2080 floats
    float* out      = (float*)d_out;

    prep_kernel<<<512, 256, 0, stream>>>(x, y, Zc, norms);
    gemm_epi<<<NBLK2, 512, 0, stream>>>(Zc, norms, sig, partials);
    finalize_kernel<<<1, 256, 0, stream>>>(partials, out);
}